// Round 5
// baseline (889.617 us; speedup 1.0000x reference)
//
#include <hip/hip_runtime.h>

#define N_NODES 50000
#define N_EDGES 800000
#define DD 128
#define GG 256
#define LL 4
#define EPSV 1e-5f
#define NB 196  // ceil(N_NODES/256)
#define AGG_BLOCKS 1024  // R3: 3125 blocks thrashed caches; keep 1024, add per-wave ILP instead

// ---------------- bf16 helpers ----------------
static __device__ __forceinline__ unsigned bf16pack(float a, float b) {
    unsigned ua = __float_as_uint(a), ub = __float_as_uint(b);
    ua = (ua + 0x7FFFu + ((ua >> 16) & 1u)) >> 16;     // RNE
    ub = (ub + 0x7FFFu + ((ub >> 16) & 1u)) >> 16;
    return ua | (ub << 16);
}
static __device__ __forceinline__ float2 bf16unpack(unsigned u) {
    float2 r;
    r.x = __uint_as_float(u << 16);
    r.y = __uint_as_float(u & 0xFFFF0000u);
    return r;
}

// ---------------- setup kernels ----------------

__global__ void count_deg_kernel(const int* __restrict__ ei, const float* __restrict__ w,
                                 int* __restrict__ counts, float* __restrict__ deg) {
    int e = blockIdx.x * 256 + threadIdx.x;
    if (e < N_EDGES) {
        int d = ei[N_EDGES + e];
        atomicAdd(&counts[d], 1);
        atomicAdd(&deg[d], w[e]);
    }
}

__global__ void dinv_kernel(const float* __restrict__ deg, float* __restrict__ dinv) {
    int i = blockIdx.x * 256 + threadIdx.x;
    if (i < N_NODES) {
        float d = deg[i] + 2.0f;  // self-loop weight 2.0
        dinv[i] = rsqrtf(fmaxf(d, EPSV));
    }
}

// hierarchical scan, stage 1: per-block (256-node) sums of counts
__global__ __launch_bounds__(256) void blocksum_kernel(const int* __restrict__ counts,
                                                       int* __restrict__ bsums) {
    int i = blockIdx.x * 256 + threadIdx.x;
    int v = (i < N_NODES) ? counts[i] : 0;
    for (int off = 32; off; off >>= 1) v += __shfl_down(v, off);
    __shared__ int s[4];
    if ((threadIdx.x & 63) == 0) s[threadIdx.x >> 6] = v;
    __syncthreads();
    if (threadIdx.x == 0) bsums[blockIdx.x] = s[0] + s[1] + s[2] + s[3];
}

// stage 2: exclusive scan of the 196 block sums (single tiny block)
__global__ __launch_bounds__(256) void scan_bsums_kernel(const int* __restrict__ bsums,
                                                         int* __restrict__ boffs,
                                                         int* __restrict__ rowptr) {
    __shared__ int s[256];
    int t = threadIdx.x;
    int v = (t < NB) ? bsums[t] : 0;
    s[t] = v;
    __syncthreads();
    for (int off = 1; off < 256; off <<= 1) {
        int u = (t >= off) ? s[t - off] : 0;
        __syncthreads();
        s[t] += u;
        __syncthreads();
    }
    if (t < NB) boffs[t] = s[t] - v;  // exclusive
    if (t == 0) rowptr[N_NODES] = N_EDGES;
}

// stage 3: per-block exclusive scan + block offset -> rowptr/cursor
__global__ __launch_bounds__(256) void rowptr_kernel(const int* __restrict__ counts,
                                                     const int* __restrict__ boffs,
                                                     int* __restrict__ rowptr,
                                                     int* __restrict__ cursor) {
    __shared__ int s[256];
    int i = blockIdx.x * 256 + threadIdx.x;
    int t = threadIdx.x;
    int c = (i < N_NODES) ? counts[i] : 0;
    s[t] = c;
    __syncthreads();
    for (int off = 1; off < 256; off <<= 1) {
        int u = (t >= off) ? s[t - off] : 0;
        __syncthreads();
        s[t] += u;
        __syncthreads();
    }
    if (i < N_NODES) {
        int r = boffs[blockIdx.x] + s[t] - c;
        rowptr[i] = r;
        cursor[i] = r;
    }
}

// pack {src, norm} into one uint2 -> single 8B scattered store (was two 4B stores)
__global__ void fill_kernel(const int* __restrict__ ei, const float* __restrict__ w,
                            const float* __restrict__ dinv, int* __restrict__ cursor,
                            uint2* __restrict__ edat) {
    int e = blockIdx.x * 256 + threadIdx.x;
    if (e < N_EDGES) {
        int s_ = ei[e];
        int d = ei[N_EDGES + e];
        int pos = atomicAdd(&cursor[d], 1);
        edat[pos] = make_uint2((unsigned)s_, __float_as_uint(dinv[s_] * w[e] * dinv[d]));
    }
}

// ---------------- GEMM: out[n,128] = act(A)[n,128] @ W[128,128] (+bias) ----------------
// act = affine(g,beta)+relu if AFFINE.  STATS: col sum/sumsq.  OUTBF16: write packed bf16 pairs.

template <bool AFFINE, bool STATS, bool BIAS, bool OUTBF16>
__global__ __launch_bounds__(256) void gemm128(const float* __restrict__ A, int n,
                                               const float* __restrict__ W,
                                               const float* __restrict__ bias,
                                               const float* __restrict__ aff,
                                               void* __restrict__ outv,
                                               float* __restrict__ stats) {
    __shared__ float As[128][64];  // As[k][r] (transposed)
    __shared__ float Ws[128][64];  // Ws[k][c]
    int tid = threadIdx.x;
    int row0 = blockIdx.y * 64;
    int col0 = blockIdx.x * 64;

    {   // load + transform A tile
        int rsub = tid >> 5;         // 0..7
        int k4 = (tid & 31) * 4;     // 0..124
        for (int it = 0; it < 8; ++it) {
            int r = it * 8 + rsub;
            int row = row0 + r;
            float4 v = make_float4(0.f, 0.f, 0.f, 0.f);
            if (row < n) v = *(const float4*)&A[(size_t)row * 128 + k4];
            if (AFFINE) {
                float4 g = *(const float4*)&aff[k4];
                float4 bb = *(const float4*)&aff[128 + k4];
                v.x = fmaxf(v.x * g.x + bb.x, 0.f);
                v.y = fmaxf(v.y * g.y + bb.y, 0.f);
                v.z = fmaxf(v.z * g.z + bb.z, 0.f);
                v.w = fmaxf(v.w * g.w + bb.w, 0.f);
            }
            As[k4 + 0][r] = v.x;
            As[k4 + 1][r] = v.y;
            As[k4 + 2][r] = v.z;
            As[k4 + 3][r] = v.w;
        }
    }
    {   // load W tile
        int krow = tid >> 4;          // 0..15
        int c4 = (tid & 15) * 4;      // 0..60
        for (int it = 0; it < 8; ++it) {
            int k = it * 16 + krow;
            *(float4*)&Ws[k][c4] = *(const float4*)&W[k * 128 + col0 + c4];
        }
    }
    __syncthreads();

    int ty = tid >> 4, tx = tid & 15;
    float acc[4][4];
#pragma unroll
    for (int i = 0; i < 4; i++)
#pragma unroll
        for (int j = 0; j < 4; j++) acc[i][j] = 0.f;

#pragma unroll 4
    for (int k = 0; k < 128; k++) {
        float4 a = *(const float4*)&As[k][ty * 4];
        float4 b = *(const float4*)&Ws[k][tx * 4];
        float av[4] = {a.x, a.y, a.z, a.w};
        float bv[4] = {b.x, b.y, b.z, b.w};
#pragma unroll
        for (int i = 0; i < 4; i++)
#pragma unroll
            for (int j = 0; j < 4; j++) acc[i][j] += av[i] * bv[j];
    }

    float csum[4] = {0, 0, 0, 0}, csq[4] = {0, 0, 0, 0};
#pragma unroll
    for (int i = 0; i < 4; i++) {
        int row = row0 + ty * 4 + i;
        if (row < n) {
            int c = col0 + tx * 4;
            if (OUTBF16) {
                uint2 p;
                p.x = bf16pack(acc[i][0], acc[i][1]);
                p.y = bf16pack(acc[i][2], acc[i][3]);
                *(uint2*)&((unsigned*)outv)[((size_t)row * 128 + c) >> 1] = p;
            } else {
#pragma unroll
                for (int j = 0; j < 4; j++) {
                    float v = acc[i][j];
                    if (BIAS) v += bias[c + j];
                    ((float*)outv)[(size_t)row * 128 + c + j] = v;
                    if (STATS) {
                        csum[j] += v;
                        csq[j] += v * v;
                    }
                }
            }
        }
    }
    if (STATS) {
        // reuse As storage for the 128-float partial buffers
        float* ps = &As[0][0];
        float* pq = &As[0][0] + 64;
        __syncthreads();
        if (tid < 64) { ps[tid] = 0.f; pq[tid] = 0.f; }
        __syncthreads();
#pragma unroll
        for (int j = 0; j < 4; j++) {
            atomicAdd(&ps[tx * 4 + j], csum[j]);
            atomicAdd(&pq[tx * 4 + j], csq[j]);
        }
        __syncthreads();
        if (tid < 64) {
            atomicAdd(&stats[col0 + tid], ps[tid]);
            atomicAdd(&stats[128 + col0 + tid], pq[tid]);
        }
    }
}

// ---------------- BN affine param kernel ----------------
__global__ void affine_kernel(const float* __restrict__ stats, const float* __restrict__ s,
                              const float* __restrict__ b, float* __restrict__ aff, float invN) {
    int i = threadIdx.x;  // 128
    float mean = stats[i] * invN;
    float var = fmaxf(stats[128 + i] * invN - mean * mean, 0.f);
    float g = s[i] * rsqrtf(var + EPSV);
    aff[i] = g;
    aff[128 + i] = b[i] - mean * g;
}

// ---------------- aggregation ----------------
// Two independent nodes per wave (p and p+N/2), 2 edges each per iter -> 8 gathers in
// flight per wave (latency-bound fix: ILP not TLP; R3 showed extra waves thrash L2/L3).
__global__ __launch_bounds__(256) void agg_kernel(const unsigned* __restrict__ hT,
                                                  const int* __restrict__ rowptr,
                                                  const uint2* __restrict__ edat,
                                                  const float* __restrict__ dinv,
                                                  const float* __restrict__ convb,
                                                  float* __restrict__ out,
                                                  float* __restrict__ stats) {
    __shared__ float ps[4][256];
    int wave = threadIdx.x >> 6, lane = threadIdx.x & 63;
    int d0 = lane * 2;
    float2 bb = *(const float2*)&convb[d0];
    float sum0 = 0, sum1 = 0, sq0 = 0, sq1 = 0;
    const int HALF = N_NODES / 2;
    for (int p = blockIdx.x * 4 + wave; p < HALF; p += AGG_BLOCKS * 4) {
        int i0 = p, i1 = p + HALF;
        float di0 = dinv[i0], di1 = dinv[i1];
        float2 hv0 = bf16unpack(hT[(size_t)i0 * 64 + lane]);
        float2 hv1 = bf16unpack(hT[(size_t)i1 * 64 + lane]);
        float sn0 = 2.0f * di0 * di0, sn1 = 2.0f * di1 * di1;
        float ax0 = sn0 * hv0.x, ay0 = sn0 * hv0.y;
        float ax1 = sn1 * hv1.x, ay1 = sn1 * hv1.y;
        int e0 = rowptr[i0], f0 = rowptr[i0 + 1];
        int e1 = rowptr[i1], f1 = rowptr[i1 + 1];
        // interleaved main loop: 2 edges from each chain -> 4 gathers + 4 edge loads in flight
        while (e0 + 1 < f0 && e1 + 1 < f1) {
            uint2 a0 = edat[e0], a1 = edat[e0 + 1];
            uint2 b0 = edat[e1], b1 = edat[e1 + 1];
            float2 ha0 = bf16unpack(hT[(size_t)a0.x * 64 + lane]);
            float2 ha1 = bf16unpack(hT[(size_t)a1.x * 64 + lane]);
            float2 hb0 = bf16unpack(hT[(size_t)b0.x * 64 + lane]);
            float2 hb1 = bf16unpack(hT[(size_t)b1.x * 64 + lane]);
            float na0 = __uint_as_float(a0.y), na1 = __uint_as_float(a1.y);
            float nb0 = __uint_as_float(b0.y), nb1 = __uint_as_float(b1.y);
            ax0 += na0 * ha0.x + na1 * ha1.x;
            ay0 += na0 * ha0.y + na1 * ha1.y;
            ax1 += nb0 * hb0.x + nb1 * hb1.x;
            ay1 += nb0 * hb0.y + nb1 * hb1.y;
            e0 += 2;
            e1 += 2;
        }
        // drain chain 0 (unroll 2)
        for (; e0 + 1 < f0; e0 += 2) {
            uint2 a0 = edat[e0], a1 = edat[e0 + 1];
            float2 ha0 = bf16unpack(hT[(size_t)a0.x * 64 + lane]);
            float2 ha1 = bf16unpack(hT[(size_t)a1.x * 64 + lane]);
            float na0 = __uint_as_float(a0.y), na1 = __uint_as_float(a1.y);
            ax0 += na0 * ha0.x + na1 * ha1.x;
            ay0 += na0 * ha0.y + na1 * ha1.y;
        }
        if (e0 < f0) {
            uint2 a0 = edat[e0];
            float2 ha0 = bf16unpack(hT[(size_t)a0.x * 64 + lane]);
            float na0 = __uint_as_float(a0.y);
            ax0 += na0 * ha0.x;
            ay0 += na0 * ha0.y;
        }
        // drain chain 1 (unroll 2)
        for (; e1 + 1 < f1; e1 += 2) {
            uint2 b0 = edat[e1], b1 = edat[e1 + 1];
            float2 hb0 = bf16unpack(hT[(size_t)b0.x * 64 + lane]);
            float2 hb1 = bf16unpack(hT[(size_t)b1.x * 64 + lane]);
            float nb0 = __uint_as_float(b0.y), nb1 = __uint_as_float(b1.y);
            ax1 += nb0 * hb0.x + nb1 * hb1.x;
            ay1 += nb0 * hb0.y + nb1 * hb1.y;
        }
        if (e1 < f1) {
            uint2 b0 = edat[e1];
            float2 hb0 = bf16unpack(hT[(size_t)b0.x * 64 + lane]);
            float nb0 = __uint_as_float(b0.y);
            ax1 += nb0 * hb0.x;
            ay1 += nb0 * hb0.y;
        }
        float ox0 = ax0 + bb.x, oy0 = ay0 + bb.y;
        float ox1 = ax1 + bb.x, oy1 = ay1 + bb.y;
        *(float2*)&out[(size_t)i0 * 128 + d0] = make_float2(ox0, oy0);
        *(float2*)&out[(size_t)i1 * 128 + d0] = make_float2(ox1, oy1);
        sum0 += ox0 + ox1;
        sum1 += oy0 + oy1;
        sq0 += ox0 * ox0 + ox1 * ox1;
        sq1 += oy0 * oy0 + oy1 * oy1;
    }
    ps[wave][d0] = sum0;
    ps[wave][d0 + 1] = sum1;
    ps[wave][128 + d0] = sq0;
    ps[wave][128 + d0 + 1] = sq1;
    __syncthreads();
    int t = threadIdx.x;
    float v = ps[0][t] + ps[1][t] + ps[2][t] + ps[3][t];
    atomicAdd(&stats[t], v);
}

// ---------------- pooling (batch is sorted) ----------------
__global__ __launch_bounds__(256) void pool_kernel(const float* __restrict__ h,
                                                   const float* __restrict__ aff,
                                                   const int* __restrict__ batch,
                                                   float* __restrict__ pooled,
                                                   float* __restrict__ cnt) {
    int base = blockIdx.x * 256;
    if (base >= N_NODES) return;
    int last = min(base + 255, N_NODES - 1);
    int bmin = batch[base], bmax = batch[last];
    int wave = threadIdx.x >> 6, lane = threadIdx.x & 63;
    int d0 = lane * 2;
    __shared__ float acc[4][128];
    __shared__ int ccnt[4];
    float ga0 = aff[d0], ga1 = aff[d0 + 1];
    float gb0 = aff[128 + d0], gb1 = aff[128 + d0 + 1];
    for (int g = bmin; g <= bmax; ++g) {
        float ax = 0.f, ay = 0.f;
        int local = 0;
        for (int j = wave; j < 256; j += 4) {
            int i = base + j;
            if (i < N_NODES && batch[i] == g) {
                float2 hv = *(const float2*)&h[(size_t)i * 128 + d0];
                ax += fmaxf(hv.x * ga0 + gb0, 0.f);
                ay += fmaxf(hv.y * ga1 + gb1, 0.f);
                local++;
            }
        }
        acc[wave][d0] = ax;
        acc[wave][d0 + 1] = ay;
        if (lane == 0) ccnt[wave] = local;
        __syncthreads();
        if (threadIdx.x < 128) {
            float t = acc[0][threadIdx.x] + acc[1][threadIdx.x] + acc[2][threadIdx.x] +
                      acc[3][threadIdx.x];
            atomicAdd(&pooled[g * 128 + threadIdx.x], t);
        } else if (threadIdx.x == 128) {
            atomicAdd(&cnt[g], (float)(ccnt[0] + ccnt[1] + ccnt[2] + ccnt[3]));
        }
        __syncthreads();
    }
}

__global__ void pooldiv_kernel(float* __restrict__ pooled, const float* __restrict__ cnt) {
    int idx = blockIdx.x * 256 + threadIdx.x;
    if (idx < GG * 128) {
        int g = idx >> 7;
        pooled[idx] *= 1.0f / fmaxf(cnt[g], 1.0f);
    }
}

// ---------------- output head ----------------
__global__ void out_kernel(const float* __restrict__ Z, const float* __restrict__ aff,
                           const float* __restrict__ outW, const float* __restrict__ outb,
                           float* __restrict__ out) {
    int g = blockIdx.x;
    int lane = threadIdx.x;  // 64
    int d0 = lane * 2;
    float2 z = *(const float2*)&Z[(size_t)g * 128 + d0];
    float s = fmaxf(z.x * aff[d0] + aff[128 + d0], 0.f) * outW[d0] +
              fmaxf(z.y * aff[d0 + 1] + aff[128 + d0 + 1], 0.f) * outW[d0 + 1];
    for (int off = 32; off; off >>= 1) s += __shfl_down(s, off);
    if (lane == 0) out[g] = s + outb[0];
}

// ---------------- host ----------------
extern "C" void kernel_launch(void* const* d_in, const int* in_sizes, int n_in,
                              void* d_out, int out_size, void* d_ws, size_t ws_size,
                              hipStream_t stream) {
    const float* x         = (const float*)d_in[0];
    const int*   ei        = (const int*)d_in[1];
    const float* ew        = (const float*)d_in[2];
    const int*   batch     = (const int*)d_in[3];
    const float* pre_W     = (const float*)d_in[4];
    const float* pre_b     = (const float*)d_in[5];
    const float* pre_bn_s  = (const float*)d_in[6];
    const float* pre_bn_b  = (const float*)d_in[7];
    const float* convW     = (const float*)d_in[8];
    const float* convb     = (const float*)d_in[9];
    const float* bn_s      = (const float*)d_in[10];
    const float* bn_b      = (const float*)d_in[11];
    const float* post_W    = (const float*)d_in[12];
    const float* post_b    = (const float*)d_in[13];
    const float* post_bn_s = (const float*)d_in[14];
    const float* post_bn_b = (const float*)d_in[15];
    const float* out_W     = (const float*)d_in[16];
    const float* out_b     = (const float*)d_in[17];

    float* ws = (float*)d_ws;
    float* deg    = ws;                        // N
    int*   counts = (int*)(ws + N_NODES);      // N
    float* stats  = ws + 2 * N_NODES;          // 6*256
    float* pooled = stats + 6 * 256;           // 256*128
    float* cnt    = pooled + GG * 128;         // 256
    size_t zero_floats = 2 * N_NODES + 6 * 256 + GG * 128 + GG;
    float* Z      = cnt + GG;                  // 256*128
    float* aff    = Z + GG * 128;              // 6*256
    int*   rowptr = (int*)(aff + 6 * 256);     // N+1
    int*   cursor = rowptr + N_NODES + 1;      // N
    int*   bsums  = cursor + N_NODES;          // NB
    int*   boffs  = bsums + NB;                // NB
    size_t eoff = (size_t)((int*)(boffs + NB) - (int*)ws);
    eoff = (eoff + 1) & ~(size_t)1;            // 8B align for uint2
    uint2* edat   = (uint2*)(ws + eoff);       // E uint2 = 2E words
    float* dinv   = ws + eoff + 2 * (size_t)N_EDGES;  // N
    size_t off = eoff + 2 * (size_t)N_EDGES + N_NODES;
    off = (off + 3) & ~(size_t)3;              // 16B align
    float* hA = ws + off;                      // N*128 fp32
    unsigned* hB = (unsigned*)(hA + (size_t)N_NODES * 128);  // N*64 packed bf16 pairs

    hipMemsetAsync(d_ws, 0, zero_floats * sizeof(float), stream);
    count_deg_kernel<<<(N_EDGES + 255) / 256, 256, 0, stream>>>(ei, ew, counts, deg);
    dinv_kernel<<<(N_NODES + 255) / 256, 256, 0, stream>>>(deg, dinv);
    blocksum_kernel<<<NB, 256, 0, stream>>>(counts, bsums);
    scan_bsums_kernel<<<1, 256, 0, stream>>>(bsums, boffs, rowptr);
    rowptr_kernel<<<NB, 256, 0, stream>>>(counts, boffs, rowptr, cursor);
    fill_kernel<<<(N_EDGES + 255) / 256, 256, 0, stream>>>(ei, ew, dinv, cursor, edat);

    dim3 gN(2, (N_NODES + 63) / 64);
    // pre FC: hA = x @ pre_W + pre_b, stats0 (fp32 out)
    gemm128<false, true, true, false><<<gN, 256, 0, stream>>>(x, N_NODES, pre_W, pre_b, nullptr,
                                                              hA, stats + 0);
    affine_kernel<<<1, 128, 0, stream>>>(stats + 0, pre_bn_s, pre_bn_b, aff + 0,
                                         1.0f / N_NODES);
    for (int l = 0; l < LL; l++) {
        // hB = bf16(relu(bn(hA)) @ convW[l])
        gemm128<true, false, false, true><<<gN, 256, 0, stream>>>(
            hA, N_NODES, convW + l * 128 * 128, nullptr, aff + l * 256, hB, nullptr);
        // hA = scatter(hB) + convb[l], stats_{l+1}
        agg_kernel<<<AGG_BLOCKS, 256, 0, stream>>>(hB, rowptr, edat, dinv,
                                                   convb + l * 128, hA,
                                                   stats + (l + 1) * 256);
        affine_kernel<<<1, 128, 0, stream>>>(stats + (l + 1) * 256, bn_s + l * 128,
                                             bn_b + l * 128, aff + (l + 1) * 256,
                                             1.0f / N_NODES);
    }
    // mean pool of relu(bn(hA))
    pool_kernel<<<(N_NODES + 255) / 256, 256, 0, stream>>>(hA, aff + 4 * 256, batch, pooled, cnt);
    pooldiv_kernel<<<(GG * 128 + 255) / 256, 256, 0, stream>>>(pooled, cnt);
    // post FC
    dim3 gP(2, 4);
    gemm128<false, true, true, false><<<gP, 256, 0, stream>>>(pooled, GG, post_W, post_b, nullptr,
                                                              Z, stats + 5 * 256);
    affine_kernel<<<1, 128, 0, stream>>>(stats + 5 * 256, post_bn_s, post_bn_b, aff + 5 * 256,
                                         1.0f / GG);
    out_kernel<<<GG, 64, 0, stream>>>(Z, aff + 5 * 256, out_W, out_b, (float*)d_out);
}

// Round 6
// 702.790 us; speedup vs baseline: 1.2658x; 1.2658x over previous
//
#include <hip/hip_runtime.h>

#define N_NODES 50000
#define N_EDGES 800000
#define DD 128
#define GG 256
#define LL 4
#define EPSV 1e-5f
#define NB 196  // ceil(N_NODES/256)
#define AGG_BLOCKS 1024  // R3: more TLP thrashed; R5: more ILP neutral -> gather plateau ~3.2TB/s
#define GEMM_BLOCKS 782  // ceil(N/64)

typedef __attribute__((ext_vector_type(8))) short s16x8;    // 8 bf16 (4 VGPRs)
typedef __attribute__((ext_vector_type(4))) float f32x4;    // 4 fp32 acc

// ---------------- bf16 helpers ----------------
static __device__ __forceinline__ unsigned bf16pack(float a, float b) {
    unsigned ua = __float_as_uint(a), ub = __float_as_uint(b);
    ua = (ua + 0x7FFFu + ((ua >> 16) & 1u)) >> 16;  // RNE
    ub = (ub + 0x7FFFu + ((ub >> 16) & 1u)) >> 16;
    return ua | (ub << 16);
}
static __device__ __forceinline__ unsigned short bf16r(float a) {
    unsigned u = __float_as_uint(a);
    u = (u + 0x7FFFu + ((u >> 16) & 1u)) >> 16;
    return (unsigned short)u;
}
static __device__ __forceinline__ float2 bf16unpack(unsigned u) {
    float2 r;
    r.x = __uint_as_float(u << 16);
    r.y = __uint_as_float(u & 0xFFFF0000u);
    return r;
}

// ---------------- setup kernels ----------------

// counts/deg interleaved: cd[2i]=count(int bits), cd[2i+1]=deg -> both atomics same cache line
__global__ void count_deg_kernel(const int* __restrict__ ei, const float* __restrict__ w,
                                 float* __restrict__ cd) {
    int e = blockIdx.x * 256 + threadIdx.x;
    if (e < N_EDGES) {
        int d = ei[N_EDGES + e];
        atomicAdd(&((int*)cd)[2 * d], 1);
        atomicAdd(&cd[2 * d + 1], w[e]);
    }
}

__global__ void dinv_kernel(const float* __restrict__ cd, float* __restrict__ dinv) {
    int i = blockIdx.x * 256 + threadIdx.x;
    if (i < N_NODES) {
        float d = cd[2 * i + 1] + 2.0f;  // self-loop weight 2.0
        dinv[i] = rsqrtf(fmaxf(d, EPSV));
    }
}

__global__ __launch_bounds__(256) void blocksum_kernel(const float* __restrict__ cd,
                                                       int* __restrict__ bsums) {
    int i = blockIdx.x * 256 + threadIdx.x;
    int v = (i < N_NODES) ? ((const int*)cd)[2 * i] : 0;
    for (int off = 32; off; off >>= 1) v += __shfl_down(v, off);
    __shared__ int s[4];
    if ((threadIdx.x & 63) == 0) s[threadIdx.x >> 6] = v;
    __syncthreads();
    if (threadIdx.x == 0) bsums[blockIdx.x] = s[0] + s[1] + s[2] + s[3];
}

__global__ __launch_bounds__(256) void scan_bsums_kernel(const int* __restrict__ bsums,
                                                         int* __restrict__ boffs,
                                                         int* __restrict__ rowptr) {
    __shared__ int s[256];
    int t = threadIdx.x;
    int v = (t < NB) ? bsums[t] : 0;
    s[t] = v;
    __syncthreads();
    for (int off = 1; off < 256; off <<= 1) {
        int u = (t >= off) ? s[t - off] : 0;
        __syncthreads();
        s[t] += u;
        __syncthreads();
    }
    if (t < NB) boffs[t] = s[t] - v;  // exclusive
    if (t == 0) rowptr[N_NODES] = N_EDGES;
}

__global__ __launch_bounds__(256) void rowptr_kernel(const float* __restrict__ cd,
                                                     const int* __restrict__ boffs,
                                                     int* __restrict__ rowptr,
                                                     int* __restrict__ cursor) {
    __shared__ int s[256];
    int i = blockIdx.x * 256 + threadIdx.x;
    int t = threadIdx.x;
    int c = (i < N_NODES) ? ((const int*)cd)[2 * i] : 0;
    s[t] = c;
    __syncthreads();
    for (int off = 1; off < 256; off <<= 1) {
        int u = (t >= off) ? s[t - off] : 0;
        __syncthreads();
        s[t] += u;
        __syncthreads();
    }
    if (i < N_NODES) {
        int r = boffs[blockIdx.x] + s[t] - c;
        rowptr[i] = r;
        cursor[i] = r;
    }
}

__global__ void fill_kernel(const int* __restrict__ ei, const float* __restrict__ w,
                            const float* __restrict__ dinv, int* __restrict__ cursor,
                            uint2* __restrict__ edat) {
    int e = blockIdx.x * 256 + threadIdx.x;
    if (e < N_EDGES) {
        int s_ = ei[e];
        int d = ei[N_EDGES + e];
        int pos = atomicAdd(&cursor[d], 1);
        edat[pos] = make_uint2((unsigned)s_, __float_as_uint(dinv[s_] * w[e] * dinv[d]));
    }
}

// ---------------- weight prep: fp32 W[k][n] -> fragment-ordered bf16 ----------------
// frag order: element W[k][n]: nt=n>>4, nl=n&15, kc=k>>5, q=(k>>3)&3, j=k&7
// linear = (((nt*4+kc)*4+q)*16+nl)*8 + j.   l=0: pre_W, l=1..4: convW[l-1]
__global__ void wprep_kernel(const float* __restrict__ preW, const float* __restrict__ convW,
                             unsigned short* __restrict__ Wf) {
    int idx = blockIdx.x * 256 + threadIdx.x;  // 5*16384
    if (idx >= 5 * 16384) return;
    int l = idx >> 14, kn = idx & 16383;
    int k = kn >> 7, nn = kn & 127;
    float v = (l == 0) ? preW[kn] : convW[(l - 1) * 16384 + kn];
    int nt = nn >> 4, nl = nn & 15, kc = k >> 5, q = (k >> 3) & 3, j = k & 7;
    Wf[(size_t)l * 16384 + ((((nt * 4 + kc) * 4 + q) * 16 + nl) * 8 + j)] = bf16r(v);
}

// ---------------- MFMA GEMM: out[n,128] = act(A)[n,128] @ W[128,128] ----------------
// AFFINE: act = relu(A*g+beta), g/beta computed in-kernel from stats+bn params.
// STATS: accumulate col sum/sumsq of (out+bias).  OUTBF16: packed bf16-pair output.
// 64-row blocks, 4 waves; each wave computes a 16x128 strip with 32 mfma_f32_16x16x32_bf16.
template <bool AFFINE, bool STATS, bool OUTBF16>
__global__ __launch_bounds__(256) void gemm_mfma(const float* __restrict__ A, int n,
                                                 const uint4* __restrict__ Wf,
                                                 const float* __restrict__ stats_in,
                                                 const float* __restrict__ bn_sc,
                                                 const float* __restrict__ bn_bi,
                                                 const float* __restrict__ bias,
                                                 void* __restrict__ outv,
                                                 float* __restrict__ stats_out) {
    __shared__ unsigned short Af[8192];  // A frags: (((w*4+kc)*4+q)*16+mrow)*8 + j
    __shared__ float WC[8448];           // W frags (16384 bf16 = 32KB) then C tile 64x132 fp32
    __shared__ float affg[128], affb[128];
    int t = threadIdx.x;
    int row0 = blockIdx.x * 64;

    if (AFFINE) {
        if (t < 128) {
            float mean = stats_in[t] * (1.0f / N_NODES);
            float var = fmaxf(stats_in[128 + t] * (1.0f / N_NODES) - mean * mean, 0.f);
            float g = bn_sc[t] * rsqrtf(var + EPSV);
            affg[t] = g;
            affb[t] = bn_bi[t] - mean * g;
        }
        __syncthreads();
    }
    {  // stage W fragments: flat conflict-free copy (2048 uint4)
        uint4* Wl = (uint4*)WC;
#pragma unroll
        for (int it = 0; it < 8; ++it) Wl[t + it * 256] = Wf[t + it * 256];
    }
    {  // stage A into fragment order (bf16), affine+relu fused
#pragma unroll
        for (int it = 0; it < 8; ++it) {
            int f = t * 4 + it * 1024;  // flat float idx in 64x128 tile
            int r = f >> 7, c = f & 127;
            int row = row0 + r;
            float4 v = make_float4(0.f, 0.f, 0.f, 0.f);
            if (row < n) v = *(const float4*)&A[(size_t)row * 128 + c];
            if (AFFINE) {
                float4 g = *(float4*)&affg[c];
                float4 bb = *(float4*)&affb[c];
                v.x = fmaxf(v.x * g.x + bb.x, 0.f);
                v.y = fmaxf(v.y * g.y + bb.y, 0.f);
                v.z = fmaxf(v.z * g.z + bb.z, 0.f);
                v.w = fmaxf(v.w * g.w + bb.w, 0.f);
            }
            int w = r >> 4, mrow = r & 15, kc = c >> 5, q = (c >> 3) & 3, jo = c & 7;
            unsigned short* dst = &Af[(((w * 4 + kc) * 4 + q) * 16 + mrow) * 8 + jo];
            *(uint2*)dst = make_uint2(bf16pack(v.x, v.y), bf16pack(v.z, v.w));
        }
    }
    __syncthreads();

    int wv = t >> 6, lane = t & 63, q = lane >> 4, ml = lane & 15;
    f32x4 acc[8];
#pragma unroll
    for (int nt = 0; nt < 8; nt++) acc[nt] = (f32x4){0.f, 0.f, 0.f, 0.f};
    const unsigned short* Wb = (const unsigned short*)WC;
#pragma unroll
    for (int kc = 0; kc < 4; kc++) {
        s16x8 a = *(const s16x8*)&Af[(((wv * 4 + kc) * 4 + q) * 16 + ml) * 8];
#pragma unroll
        for (int nt = 0; nt < 8; nt++) {
            s16x8 b = *(const s16x8*)&Wb[(((nt * 4 + kc) * 4 + q) * 16 + ml) * 8];
            acc[nt] = __builtin_amdgcn_mfma_f32_16x16x32_bf16(a, b, acc[nt], 0, 0, 0);
        }
    }
    __syncthreads();  // all W-frag reads done; reuse WC as C tile
    float* Cs = WC;   // [64][132]
#pragma unroll
    for (int nt = 0; nt < 8; nt++)
#pragma unroll
        for (int rr = 0; rr < 4; rr++)
            Cs[(wv * 16 + q * 4 + rr) * 132 + nt * 16 + ml] = acc[nt][rr];
    __syncthreads();

    float csum[4] = {0, 0, 0, 0}, csq[4] = {0, 0, 0, 0};
#pragma unroll
    for (int it = 0; it < 8; ++it) {
        int f = t * 4 + it * 1024;
        int r = f >> 7, c = f & 127;
        int row = row0 + r;
        if (row < n) {
            float4 v = *(float4*)&Cs[r * 132 + c];
            if (!AFFINE) {  // pre path: +bias
                v.x += bias[c];
                v.y += bias[c + 1];
                v.z += bias[c + 2];
                v.w += bias[c + 3];
            }
            if (OUTBF16) {
                uint2 p;
                p.x = bf16pack(v.x, v.y);
                p.y = bf16pack(v.z, v.w);
                *(uint2*)&((unsigned*)outv)[(size_t)row * 64 + (c >> 1)] = p;
            } else {
                *(float4*)&((float*)outv)[(size_t)row * 128 + c] = v;
            }
            if (STATS) {
                csum[0] += v.x; csq[0] += v.x * v.x;
                csum[1] += v.y; csq[1] += v.y * v.y;
                csum[2] += v.z; csq[2] += v.z * v.z;
                csum[3] += v.w; csq[3] += v.w * v.w;
            }
        }
    }
    if (STATS) {
        __syncthreads();
        if (t < 128) { affg[t] = 0.f; affb[t] = 0.f; }
        __syncthreads();
        int c = (t & 31) * 4;
#pragma unroll
        for (int j = 0; j < 4; j++) {
            atomicAdd(&affg[c + j], csum[j]);
            atomicAdd(&affb[c + j], csq[j]);
        }
        __syncthreads();
        if (t < 128) {
            atomicAdd(&stats_out[t], affg[t]);
            atomicAdd(&stats_out[128 + t], affb[t]);
        }
    }
}

// ---------------- fp32 GEMM (post FC only: 256 rows) ----------------
template <bool STATS, bool BIAS>
__global__ __launch_bounds__(256) void gemm128(const float* __restrict__ A, int n,
                                               const float* __restrict__ W,
                                               const float* __restrict__ bias,
                                               float* __restrict__ out,
                                               float* __restrict__ stats) {
    __shared__ float As[128][64];
    __shared__ float Ws[128][64];
    int tid = threadIdx.x;
    int row0 = blockIdx.y * 64;
    int col0 = blockIdx.x * 64;
    {
        int rsub = tid >> 5;
        int k4 = (tid & 31) * 4;
        for (int it = 0; it < 8; ++it) {
            int r = it * 8 + rsub;
            int row = row0 + r;
            float4 v = make_float4(0.f, 0.f, 0.f, 0.f);
            if (row < n) v = *(const float4*)&A[(size_t)row * 128 + k4];
            As[k4 + 0][r] = v.x;
            As[k4 + 1][r] = v.y;
            As[k4 + 2][r] = v.z;
            As[k4 + 3][r] = v.w;
        }
    }
    {
        int krow = tid >> 4;
        int c4 = (tid & 15) * 4;
        for (int it = 0; it < 8; ++it) {
            int k = it * 16 + krow;
            *(float4*)&Ws[k][c4] = *(const float4*)&W[k * 128 + col0 + c4];
        }
    }
    __syncthreads();
    int ty = tid >> 4, tx = tid & 15;
    float acc[4][4];
#pragma unroll
    for (int i = 0; i < 4; i++)
#pragma unroll
        for (int j = 0; j < 4; j++) acc[i][j] = 0.f;
#pragma unroll 4
    for (int k = 0; k < 128; k++) {
        float4 a = *(const float4*)&As[k][ty * 4];
        float4 b = *(const float4*)&Ws[k][tx * 4];
        float av[4] = {a.x, a.y, a.z, a.w};
        float bv[4] = {b.x, b.y, b.z, b.w};
#pragma unroll
        for (int i = 0; i < 4; i++)
#pragma unroll
            for (int j = 0; j < 4; j++) acc[i][j] += av[i] * bv[j];
    }
    float csum[4] = {0, 0, 0, 0}, csq[4] = {0, 0, 0, 0};
#pragma unroll
    for (int i = 0; i < 4; i++) {
        int row = row0 + ty * 4 + i;
        if (row < n) {
#pragma unroll
            for (int j = 0; j < 4; j++) {
                float v = acc[i][j];
                if (BIAS) v += bias[col0 + tx * 4 + j];
                out[(size_t)row * 128 + col0 + tx * 4 + j] = v;
                if (STATS) { csum[j] += v; csq[j] += v * v; }
            }
        }
    }
    if (STATS) {
        float* ps = &As[0][0];
        float* pq = &As[0][0] + 64;
        __syncthreads();
        if (tid < 64) { ps[tid] = 0.f; pq[tid] = 0.f; }
        __syncthreads();
#pragma unroll
        for (int j = 0; j < 4; j++) {
            atomicAdd(&ps[tx * 4 + j], csum[j]);
            atomicAdd(&pq[tx * 4 + j], csq[j]);
        }
        __syncthreads();
        if (tid < 64) {
            atomicAdd(&stats[col0 + tid], ps[tid]);
            atomicAdd(&stats[128 + col0 + tid], pq[tid]);
        }
    }
}

// ---------------- BN affine param kernel (post FC only) ----------------
__global__ void affine_kernel(const float* __restrict__ stats, const float* __restrict__ s,
                              const float* __restrict__ b, float* __restrict__ aff, float invN) {
    int i = threadIdx.x;  // 128
    float mean = stats[i] * invN;
    float var = fmaxf(stats[128 + i] * invN - mean * mean, 0.f);
    float g = s[i] * rsqrtf(var + EPSV);
    aff[i] = g;
    aff[128 + i] = b[i] - mean * g;
}

// ---------------- aggregation (unchanged from R5: gather plateau) ----------------
__global__ __launch_bounds__(256) void agg_kernel(const unsigned* __restrict__ hT,
                                                  const int* __restrict__ rowptr,
                                                  const uint2* __restrict__ edat,
                                                  const float* __restrict__ dinv,
                                                  const float* __restrict__ convb,
                                                  float* __restrict__ out,
                                                  float* __restrict__ stats) {
    __shared__ float ps[4][256];
    int wave = threadIdx.x >> 6, lane = threadIdx.x & 63;
    int d0 = lane * 2;
    float2 bb = *(const float2*)&convb[d0];
    float sum0 = 0, sum1 = 0, sq0 = 0, sq1 = 0;
    const int HALF = N_NODES / 2;
    for (int p = blockIdx.x * 4 + wave; p < HALF; p += AGG_BLOCKS * 4) {
        int i0 = p, i1 = p + HALF;
        float di0 = dinv[i0], di1 = dinv[i1];
        float2 hv0 = bf16unpack(hT[(size_t)i0 * 64 + lane]);
        float2 hv1 = bf16unpack(hT[(size_t)i1 * 64 + lane]);
        float sn0 = 2.0f * di0 * di0, sn1 = 2.0f * di1 * di1;
        float ax0 = sn0 * hv0.x, ay0 = sn0 * hv0.y;
        float ax1 = sn1 * hv1.x, ay1 = sn1 * hv1.y;
        int e0 = rowptr[i0], f0 = rowptr[i0 + 1];
        int e1 = rowptr[i1], f1 = rowptr[i1 + 1];
        while (e0 + 1 < f0 && e1 + 1 < f1) {
            uint2 a0 = edat[e0], a1 = edat[e0 + 1];
            uint2 b0 = edat[e1], b1 = edat[e1 + 1];
            float2 ha0 = bf16unpack(hT[(size_t)a0.x * 64 + lane]);
            float2 ha1 = bf16unpack(hT[(size_t)a1.x * 64 + lane]);
            float2 hb0 = bf16unpack(hT[(size_t)b0.x * 64 + lane]);
            float2 hb1 = bf16unpack(hT[(size_t)b1.x * 64 + lane]);
            float na0 = __uint_as_float(a0.y), na1 = __uint_as_float(a1.y);
            float nb0 = __uint_as_float(b0.y), nb1 = __uint_as_float(b1.y);
            ax0 += na0 * ha0.x + na1 * ha1.x;
            ay0 += na0 * ha0.y + na1 * ha1.y;
            ax1 += nb0 * hb0.x + nb1 * hb1.x;
            ay1 += nb0 * hb0.y + nb1 * hb1.y;
            e0 += 2;
            e1 += 2;
        }
        for (; e0 + 1 < f0; e0 += 2) {
            uint2 a0 = edat[e0], a1 = edat[e0 + 1];
            float2 ha0 = bf16unpack(hT[(size_t)a0.x * 64 + lane]);
            float2 ha1 = bf16unpack(hT[(size_t)a1.x * 64 + lane]);
            float na0 = __uint_as_float(a0.y), na1 = __uint_as_float(a1.y);
            ax0 += na0 * ha0.x + na1 * ha1.x;
            ay0 += na0 * ha0.y + na1 * ha1.y;
        }
        if (e0 < f0) {
            uint2 a0 = edat[e0];
            float2 ha0 = bf16unpack(hT[(size_t)a0.x * 64 + lane]);
            float na0 = __uint_as_float(a0.y);
            ax0 += na0 * ha0.x;
            ay0 += na0 * ha0.y;
        }
        for (; e1 + 1 < f1; e1 += 2) {
            uint2 b0 = edat[e1], b1 = edat[e1 + 1];
            float2 hb0 = bf16unpack(hT[(size_t)b0.x * 64 + lane]);
            float2 hb1 = bf16unpack(hT[(size_t)b1.x * 64 + lane]);
            float nb0 = __uint_as_float(b0.y), nb1 = __uint_as_float(b1.y);
            ax1 += nb0 * hb0.x + nb1 * hb1.x;
            ay1 += nb0 * hb0.y + nb1 * hb1.y;
        }
        if (e1 < f1) {
            uint2 b0 = edat[e1];
            float2 hb0 = bf16unpack(hT[(size_t)b0.x * 64 + lane]);
            float nb0 = __uint_as_float(b0.y);
            ax1 += nb0 * hb0.x;
            ay1 += nb0 * hb0.y;
        }
        float ox0 = ax0 + bb.x, oy0 = ay0 + bb.y;
        float ox1 = ax1 + bb.x, oy1 = ay1 + bb.y;
        *(float2*)&out[(size_t)i0 * 128 + d0] = make_float2(ox0, oy0);
        *(float2*)&out[(size_t)i1 * 128 + d0] = make_float2(ox1, oy1);
        sum0 += ox0 + ox1;
        sum1 += oy0 + oy1;
        sq0 += ox0 * ox0 + ox1 * ox1;
        sq1 += oy0 * oy0 + oy1 * oy1;
    }
    ps[wave][d0] = sum0;
    ps[wave][d0 + 1] = sum1;
    ps[wave][128 + d0] = sq0;
    ps[wave][128 + d0 + 1] = sq1;
    __syncthreads();
    int t = threadIdx.x;
    float v = ps[0][t] + ps[1][t] + ps[2][t] + ps[3][t];
    atomicAdd(&stats[t], v);
}

// ---------------- pooling: aff computed in-kernel from stats4 ----------------
__global__ __launch_bounds__(256) void pool_kernel(const float* __restrict__ h,
                                                   const float* __restrict__ stats_in,
                                                   const float* __restrict__ bn_sc,
                                                   const float* __restrict__ bn_bi,
                                                   const int* __restrict__ batch,
                                                   float* __restrict__ pooled,
                                                   float* __restrict__ cnt) {
    int base = blockIdx.x * 256;
    if (base >= N_NODES) return;
    __shared__ float affg[128], affb[128];
    if (threadIdx.x < 128) {
        int i = threadIdx.x;
        float mean = stats_in[i] * (1.0f / N_NODES);
        float var = fmaxf(stats_in[128 + i] * (1.0f / N_NODES) - mean * mean, 0.f);
        float g = bn_sc[i] * rsqrtf(var + EPSV);
        affg[i] = g;
        affb[i] = bn_bi[i] - mean * g;
    }
    __syncthreads();
    int last = min(base + 255, N_NODES - 1);
    int bmin = batch[base], bmax = batch[last];
    int wave = threadIdx.x >> 6, lane = threadIdx.x & 63;
    int d0 = lane * 2;
    __shared__ float acc[4][128];
    __shared__ int ccnt[4];
    float ga0 = affg[d0], ga1 = affg[d0 + 1];
    float gb0 = affb[d0], gb1 = affb[d0 + 1];
    for (int g = bmin; g <= bmax; ++g) {
        float ax = 0.f, ay = 0.f;
        int local = 0;
        for (int j = wave; j < 256; j += 4) {
            int i = base + j;
            if (i < N_NODES && batch[i] == g) {
                float2 hv = *(const float2*)&h[(size_t)i * 128 + d0];
                ax += fmaxf(hv.x * ga0 + gb0, 0.f);
                ay += fmaxf(hv.y * ga1 + gb1, 0.f);
                local++;
            }
        }
        acc[wave][d0] = ax;
        acc[wave][d0 + 1] = ay;
        if (lane == 0) ccnt[wave] = local;
        __syncthreads();
        if (threadIdx.x < 128) {
            float t = acc[0][threadIdx.x] + acc[1][threadIdx.x] + acc[2][threadIdx.x] +
                      acc[3][threadIdx.x];
            atomicAdd(&pooled[g * 128 + threadIdx.x], t);
        } else if (threadIdx.x == 128) {
            atomicAdd(&cnt[g], (float)(ccnt[0] + ccnt[1] + ccnt[2] + ccnt[3]));
        }
        __syncthreads();
    }
}

__global__ void pooldiv_kernel(float* __restrict__ pooled, const float* __restrict__ cnt) {
    int idx = blockIdx.x * 256 + threadIdx.x;
    if (idx < GG * 128) {
        int g = idx >> 7;
        pooled[idx] *= 1.0f / fmaxf(cnt[g], 1.0f);
    }
}

// ---------------- output head ----------------
__global__ void out_kernel(const float* __restrict__ Z, const float* __restrict__ aff,
                           const float* __restrict__ outW, const float* __restrict__ outb,
                           float* __restrict__ out) {
    int g = blockIdx.x;
    int lane = threadIdx.x;  // 64
    int d0 = lane * 2;
    float2 z = *(const float2*)&Z[(size_t)g * 128 + d0];
    float s = fmaxf(z.x * aff[d0] + aff[128 + d0], 0.f) * outW[d0] +
              fmaxf(z.y * aff[d0 + 1] + aff[128 + d0 + 1], 0.f) * outW[d0 + 1];
    for (int off = 32; off; off >>= 1) s += __shfl_down(s, off);
    if (lane == 0) out[g] = s + outb[0];
}

// ---------------- host ----------------
extern "C" void kernel_launch(void* const* d_in, const int* in_sizes, int n_in,
                              void* d_out, int out_size, void* d_ws, size_t ws_size,
                              hipStream_t stream) {
    const float* x         = (const float*)d_in[0];
    const int*   ei        = (const int*)d_in[1];
    const float* ew        = (const float*)d_in[2];
    const int*   batch     = (const int*)d_in[3];
    const float* pre_W     = (const float*)d_in[4];
    const float* pre_b     = (const float*)d_in[5];
    const float* pre_bn_s  = (const float*)d_in[6];
    const float* pre_bn_b  = (const float*)d_in[7];
    const float* convW     = (const float*)d_in[8];
    const float* convb     = (const float*)d_in[9];
    const float* bn_s      = (const float*)d_in[10];
    const float* bn_b      = (const float*)d_in[11];
    const float* post_W    = (const float*)d_in[12];
    const float* post_b    = (const float*)d_in[13];
    const float* post_bn_s = (const float*)d_in[14];
    const float* post_bn_b = (const float*)d_in[15];
    const float* out_W     = (const float*)d_in[16];
    const float* out_b     = (const float*)d_in[17];

    float* ws = (float*)d_ws;
    float* cd     = ws;                        // 2N (counts/deg interleaved, zeroed)
    float* stats  = ws + 2 * N_NODES;          // 6*256 (zeroed)
    float* pooled = stats + 6 * 256;           // 256*128 (zeroed)
    float* cnt    = pooled + GG * 128;         // 256 (zeroed)
    size_t zero_floats = 2 * N_NODES + 6 * 256 + GG * 128 + GG;
    float* Z      = cnt + GG;                  // 256*128
    float* aff    = Z + GG * 128;              // 256 (post only)
    int*   rowptr = (int*)(aff + 256);         // N+1
    int*   cursor = rowptr + N_NODES + 1;      // N
    int*   bsums  = cursor + N_NODES;          // NB
    int*   boffs  = bsums + NB;                // NB
    size_t woff = (size_t)((float*)(boffs + NB) - ws);
    woff = (woff + 3) & ~(size_t)3;            // 16B align for uint4
    unsigned short* Wf = (unsigned short*)(ws + woff);  // 5*16384 ushort = 40960 floats
    size_t eoff = woff + 40960;
    eoff = (eoff + 1) & ~(size_t)1;            // 8B align
    uint2* edat   = (uint2*)(ws + eoff);       // E uint2
    float* dinv   = ws + eoff + 2 * (size_t)N_EDGES;  // N
    size_t off = eoff + 2 * (size_t)N_EDGES + N_NODES;
    off = (off + 3) & ~(size_t)3;
    float* hA = ws + off;                                    // N*128 fp32
    unsigned* hB = (unsigned*)(hA + (size_t)N_NODES * 128);  // N*64 packed bf16 pairs

    hipMemsetAsync(d_ws, 0, zero_floats * sizeof(float), stream);
    wprep_kernel<<<320, 256, 0, stream>>>(pre_W, convW, Wf);
    count_deg_kernel<<<(N_EDGES + 255) / 256, 256, 0, stream>>>(ei, ew, cd);
    dinv_kernel<<<(N_NODES + 255) / 256, 256, 0, stream>>>(cd, dinv);
    blocksum_kernel<<<NB, 256, 0, stream>>>(cd, bsums);
    scan_bsums_kernel<<<1, 256, 0, stream>>>(bsums, boffs, rowptr);
    rowptr_kernel<<<NB, 256, 0, stream>>>(cd, boffs, rowptr, cursor);
    fill_kernel<<<(N_EDGES + 255) / 256, 256, 0, stream>>>(ei, ew, dinv, cursor, edat);

    // pre FC: hA = x @ pre_W + pre_b (MFMA bf16), stats0
    gemm_mfma<false, true, false><<<GEMM_BLOCKS, 256, 0, stream>>>(
        x, N_NODES, (const uint4*)Wf, nullptr, nullptr, nullptr, pre_b, hA, stats + 0);
    for (int l = 0; l < LL; l++) {
        const float* sc = (l == 0) ? pre_bn_s : bn_s + (l - 1) * 128;
        const float* bi = (l == 0) ? pre_bn_b : bn_b + (l - 1) * 128;
        // hB = bf16(relu(bn(hA)) @ convW[l]) -- aff computed in-kernel from stats_l
        gemm_mfma<true, false, true><<<GEMM_BLOCKS, 256, 0, stream>>>(
            hA, N_NODES, (const uint4*)(Wf + (size_t)(1 + l) * 16384), stats + l * 256, sc, bi,
            nullptr, hB, nullptr);
        // hA = scatter(hB) + convb[l], stats_{l+1}
        agg_kernel<<<AGG_BLOCKS, 256, 0, stream>>>(hB, rowptr, edat, dinv, convb + l * 128, hA,
                                                   stats + (l + 1) * 256);
    }
    // mean pool of relu(bn(hA)) -- aff from stats4 in-kernel
    pool_kernel<<<(N_NODES + 255) / 256, 256, 0, stream>>>(hA, stats + 4 * 256, bn_s + 3 * 128,
                                                           bn_b + 3 * 128, batch, pooled, cnt);
    pooldiv_kernel<<<(GG * 128 + 255) / 256, 256, 0, stream>>>(pooled, cnt);
    // post FC (fp32, tiny)
    dim3 gP(2, 4);
    gemm128<true, true><<<gP, 256, 0, stream>>>(pooled, GG, post_W, post_b, Z, stats + 5 * 256);
    affine_kernel<<<1, 128, 0, stream>>>(stats + 5 * 256, post_bn_s, post_bn_b, aff,
                                         1.0f / GG);
    out_kernel<<<GG, 64, 0, stream>>>(Z, aff, out_W, out_b, (float*)d_out);
}